// Round 1
// baseline (858.977 us; speedup 1.0000x reference)
//
#include <hip/hip_runtime.h>

// Problem constants
#define BDIM 32
#define TDIM 512
#define HID  256
#define NHEAD 4
#define FEAT 4096   // 256*16
#define POS  16     // 4x4 spatial

typedef short v8s __attribute__((ext_vector_type(8)));
typedef float v4f __attribute__((ext_vector_type(4)));

__device__ inline ushort f2bf(float x){
  union { float f; uint u; } v; v.f = x;
  uint r = v.u + 0x7fffu + ((v.u >> 16) & 1u);
  return (ushort)(r >> 16);
}

// ---------------- K1: partial mean over T (8 segments of 64) ----------------
// grid 1024 = b(32) x seg(8) x pb(4), block 256. zpart[seg][b][4096]
__global__ __launch_bounds__(256) void k_zpart(const float* __restrict__ h,
                                               float* __restrict__ zpart){
  int blk = blockIdx.x;
  int pb = blk & 3, seg = (blk >> 2) & 7, b = blk >> 5;
  int pos4 = pb * 256 + threadIdx.x;            // float4 index 0..1023
  const float4* hp = (const float4*)h;
  int base = (b * 512 + seg * 64) * 1024 + pos4;
  float4 acc = {0.f,0.f,0.f,0.f};
  for (int t = 0; t < 64; ++t){
    float4 v = hp[base + t * 1024];
    acc.x += v.x; acc.y += v.y; acc.z += v.z; acc.w += v.w;
  }
  ((float4*)zpart)[(seg * 32 + b) * 1024 + pos4] = acc;
}

// ---------------- K2: finish mean ----------------
__global__ __launch_bounds__(256) void k_zfin(const float* __restrict__ zpart,
                                              float* __restrict__ z){
  int i = blockIdx.x * 256 + threadIdx.x;       // b*4096 + pos
  int b = i >> 12, pos = i & 4095;
  float s = 0.f;
  #pragma unroll
  for (int seg = 0; seg < 8; ++seg) s += zpart[(seg * 32 + b) * 4096 + pos];
  z[i] = s * (1.0f / 512.0f);
}

// ---------------- K3: q = Wq z + bq ; qt = (scale) Wk^T q per head ; qbias ----------------
// grid 128 = b*4+n, block 256
__global__ __launch_bounds__(256) void k_qt(const float* __restrict__ z,
                                            const float* __restrict__ Wq, const float* __restrict__ bq,
                                            const float* __restrict__ Wk, const float* __restrict__ bk,
                                            float* __restrict__ qt, float* __restrict__ qbias){
  __shared__ float zl[4096];
  __shared__ float ql[64 * 16];
  __shared__ float red[256];
  int b = blockIdx.x >> 2, n = blockIdx.x & 3;
  int tid = threadIdx.x;
  for (int i = tid; i < 4096; i += 256) zl[i] = z[b * 4096 + i];
  __syncthreads();
  int p = tid & 15, oo0 = tid >> 4;             // 16 oo x 16 p
  float qb_part = 0.f;
  #pragma unroll
  for (int it = 0; it < 4; ++it){
    int oo = oo0 + it * 16;
    int o = n * 64 + oo;
    float acc = bq[o];
    const float* wr = Wq + o * 256;
    for (int c = 0; c < 256; ++c) acc += wr[c] * zl[c * 16 + p];
    ql[oo * 16 + p] = acc;
    qb_part += acc * bk[o];
  }
  red[tid] = qb_part;
  __syncthreads();
  for (int s2 = 128; s2 > 0; s2 >>= 1){
    if (tid < s2) red[tid] += red[tid + s2];
    __syncthreads();
  }
  const float scale = 1.0f / 32.0f;             // 1/sqrt(16*64)
  if (tid == 0) qbias[b * 4 + n] = red[0] * scale;
  // qt[c][p] = scale * sum_oo ql[oo][p] * Wk[n*64+oo][c]
  for (int it = 0; it < 16; ++it){
    int c = (tid >> 4) + it * 16;
    float acc = 0.f;
    for (int oo = 0; oo < 64; ++oo) acc += ql[oo * 16 + p] * Wk[(n * 64 + oo) * 256 + c];
    qt[(b * 4 + n) * 4096 + c * 16 + p] = acc * scale;
  }
}

// ---------------- K4: sim[b,n,t] = qt . h[b,t] + qbias ----------------
// grid 1024 = b(32) x tg(32), block 256 (4 waves, each wave 4 t's)
__global__ __launch_bounds__(256) void k_sim(const float* __restrict__ h,
                                             const float* __restrict__ qt,
                                             const float* __restrict__ qbias,
                                             float* __restrict__ sim){
  __shared__ float qtl[4 * 4096];
  int b = blockIdx.x >> 5, tg = blockIdx.x & 31;
  int tid = threadIdx.x, wid = tid >> 6, lane = tid & 63;
  const float4* qsrc = (const float4*)(qt + b * 16384);
  float4* qdst = (float4*)qtl;
  for (int i = tid; i < 4096; i += 256) qdst[i] = qsrc[i];
  __syncthreads();
  float qb0 = qbias[b*4+0], qb1 = qbias[b*4+1], qb2 = qbias[b*4+2], qb3 = qbias[b*4+3];
  for (int tl = 0; tl < 4; ++tl){
    int t = tg * 16 + wid * 4 + tl;
    const float4* hp = (const float4*)h + (size_t)(b * 512 + t) * 1024;
    float a0=0.f, a1=0.f, a2=0.f, a3=0.f;
    #pragma unroll 4
    for (int kk = 0; kk < 16; ++kk){
      int pos4 = kk * 64 + lane;
      float4 hv = hp[pos4];
      float4 q0 = qdst[pos4];
      float4 q1 = qdst[1024 + pos4];
      float4 q2 = qdst[2048 + pos4];
      float4 q3 = qdst[3072 + pos4];
      a0 += hv.x*q0.x + hv.y*q0.y + hv.z*q0.z + hv.w*q0.w;
      a1 += hv.x*q1.x + hv.y*q1.y + hv.z*q1.z + hv.w*q1.w;
      a2 += hv.x*q2.x + hv.y*q2.y + hv.z*q2.z + hv.w*q2.w;
      a3 += hv.x*q3.x + hv.y*q3.y + hv.z*q3.z + hv.w*q3.w;
    }
    #pragma unroll
    for (int d = 32; d; d >>= 1){
      a0 += __shfl_xor(a0, d); a1 += __shfl_xor(a1, d);
      a2 += __shfl_xor(a2, d); a3 += __shfl_xor(a3, d);
    }
    if (lane == 0){
      float* sp = sim + (b * 4) * 512 + t;
      sp[0] = a0 + qb0; sp[512] = a1 + qb1; sp[1024] = a2 + qb2; sp[1536] = a3 + qb3;
    }
  }
}

// ---------------- K5: softmax over t per (b,n); writes att (an output) ----------------
// grid 128 = b*4+n, block 512
__global__ __launch_bounds__(512) void k_soft(const float* __restrict__ sim,
                                              float* __restrict__ att){
  __shared__ float wred[8];
  int bn = blockIdx.x, tid = threadIdx.x, lane = tid & 63, wid = tid >> 6;
  float s = sim[bn * 512 + tid];
  float m = s;
  #pragma unroll
  for (int d = 32; d; d >>= 1) m = fmaxf(m, __shfl_xor(m, d));
  if (lane == 0) wred[wid] = m;
  __syncthreads();
  float bm = wred[0];
  #pragma unroll
  for (int i = 1; i < 8; ++i) bm = fmaxf(bm, wred[i]);
  float e = expf(s - bm);
  float ss = e;
  #pragma unroll
  for (int d = 32; d; d >>= 1) ss += __shfl_xor(ss, d);
  __syncthreads();
  if (lane == 0) wred[wid] = ss;
  __syncthreads();
  float tot = 0.f;
  #pragma unroll
  for (int i = 0; i < 8; ++i) tot += wred[i];
  att[bn * 512 + tid] = e / tot;
}

// ---------------- K6: hbar partials: hbp[seg][b*4+n][4096] = sum_t att*h ----------------
// grid 1024 = b(32) x seg(8) x pb(4), block 256
__global__ __launch_bounds__(256) void k_hbar(const float* __restrict__ h,
                                              const float* __restrict__ att,
                                              float* __restrict__ hbp){
  __shared__ float al[4 * 64];
  int blk = blockIdx.x;
  int pb = blk & 3, seg = (blk >> 2) & 7, b = blk >> 5;
  int tid = threadIdx.x;
  if (tid < 256){
    int n = tid >> 6, tt = tid & 63;
    al[n * 64 + tt] = att[(b * 4 + n) * 512 + seg * 64 + tt];
  }
  __syncthreads();
  int pos4 = pb * 256 + tid;
  const float4* hp = (const float4*)h + (size_t)(b * 512 + seg * 64) * 1024 + pos4;
  float4 A0{0,0,0,0}, A1{0,0,0,0}, A2{0,0,0,0}, A3{0,0,0,0};
  for (int tt = 0; tt < 64; ++tt){
    float4 hv = hp[(size_t)tt * 1024];
    float w0 = al[tt], w1 = al[64+tt], w2 = al[128+tt], w3 = al[192+tt];
    A0.x += w0*hv.x; A0.y += w0*hv.y; A0.z += w0*hv.z; A0.w += w0*hv.w;
    A1.x += w1*hv.x; A1.y += w1*hv.y; A1.z += w1*hv.z; A1.w += w1*hv.w;
    A2.x += w2*hv.x; A2.y += w2*hv.y; A2.z += w2*hv.z; A2.w += w2*hv.w;
    A3.x += w3*hv.x; A3.y += w3*hv.y; A3.z += w3*hv.z; A3.w += w3*hv.w;
  }
  float4* dst = (float4*)hbp;
  size_t o = (size_t)(seg * 128 + b * 4) * 1024 + pos4;
  dst[o] = A0; dst[o + 1024] = A1; dst[o + 2048] = A2; dst[o + 3072] = A3;
}

// ---------------- K7: a = Wv hbar + bv ; also abf (bf16 copy of a) ----------------
// grid 128 = b*4+n, block 256
__global__ __launch_bounds__(256) void k_av(const float* __restrict__ hbp,
                                            const float* __restrict__ Wv, const float* __restrict__ bv,
                                            float* __restrict__ out_a, ushort* __restrict__ abf){
  __shared__ float hb[4096];
  int b = blockIdx.x >> 2, n = blockIdx.x & 3;
  int tid = threadIdx.x;
  for (int i = tid; i < 4096; i += 256){
    float s = 0.f;
    #pragma unroll
    for (int seg = 0; seg < 8; ++seg) s += hbp[(size_t)(seg * 128 + b * 4 + n) * 4096 + i];
    hb[i] = s;
  }
  __syncthreads();
  int p = tid & 15, oo0 = tid >> 4;
  #pragma unroll
  for (int it = 0; it < 4; ++it){
    int oo = oo0 + it * 16;
    int o = n * 64 + oo;
    float acc = bv[o];
    const float* wr = Wv + o * 256;
    for (int c = 0; c < 256; ++c) acc += wr[c] * hb[c * 16 + p];
    int f = o * 16 + p;
    out_a[b * 4096 + f] = acc;
    abf[b * 4096 + f] = f2bf(acc);
  }
}

// ---------------- K8: PostPool GEMM layer: Ypart[kc][m][o] partials via bf16 MFMA ----------------
// grid = (O/64) * 8 kchunks, block 256 (4 waves, wave = 16 o-columns)
template<int O>
__global__ __launch_bounds__(256) void k_pp(const ushort* __restrict__ X,
                                            const float* __restrict__ W,
                                            float* __restrict__ Ypart){
  constexpr int OT = O / 64;
  __shared__ ushort Wl[64 * 136];               // 64 rows x 128 k (bf16), pitch 136
  int ot = blockIdx.x % OT, kc = blockIdx.x / OT;
  int tid = threadIdx.x, wid = tid >> 6, lane = tid & 63;
  v4f acc0 = {0.f,0.f,0.f,0.f}, acc1 = {0.f,0.f,0.f,0.f};
  int r8 = tid >> 5, c4 = tid & 31;
  int m0 = lane & 15, kg = (lane >> 4) * 8;
  for (int ks = 0; ks < 4; ++ks){
    int k0 = kc * 512 + ks * 128;
    __syncthreads();
    #pragma unroll
    for (int rr = 0; rr < 8; ++rr){
      int row = rr * 8 + r8;
      float4 wv = *(const float4*)(W + (size_t)(ot * 64 + row) * 4096 + k0 + c4 * 4);
      ushort4 u; u.x = f2bf(wv.x); u.y = f2bf(wv.y); u.z = f2bf(wv.z); u.w = f2bf(wv.w);
      *(ushort4*)&Wl[row * 136 + c4 * 4] = u;
    }
    __syncthreads();
    #pragma unroll
    for (int kk = 0; kk < 4; ++kk){
      int kx = k0 + kk * 32 + kg;
      v8s a0 = *(const v8s*)(X + m0 * 4096 + kx);
      v8s a1 = *(const v8s*)(X + (m0 + 16) * 4096 + kx);
      v8s bf = *(const v8s*)&Wl[(wid * 16 + m0) * 136 + kk * 32 + kg];
      acc0 = __builtin_amdgcn_mfma_f32_16x16x32_bf16(a0, bf, acc0, 0, 0, 0);
      acc1 = __builtin_amdgcn_mfma_f32_16x16x32_bf16(a1, bf, acc1, 0, 0, 0);
    }
  }
  int o = ot * 64 + wid * 16 + m0;
  int rb = (lane >> 4) * 4;
  #pragma unroll
  for (int r = 0; r < 4; ++r){
    Ypart[(size_t)(kc * 32 + rb + r) * O + o]       = acc0[r];
    Ypart[(size_t)(kc * 32 + 16 + rb + r) * O + o]  = acc1[r];
  }
}

// ---------------- K9: sum partials + bias (+ELU -> bf16) or final split write ----------------
template<int O, bool FINAL>
__global__ __launch_bounds__(256) void k_ppfin(const float* __restrict__ Ypart,
                                               const float* __restrict__ bias,
                                               ushort* __restrict__ Xn,
                                               float* __restrict__ outp){
  int i = blockIdx.x * 256 + threadIdx.x;       // m*O + o
  int m = i / O, o = i % O;
  float s = bias[o];
  #pragma unroll
  for (int kc = 0; kc < 8; ++kc) s += Ypart[(size_t)(kc * 32 + m) * O + o];
  if (FINAL){
    if (o < 128) outp[m * 128 + o] = s;
    else         outp[4096 + m * 128 + (o - 128)] = s;
  } else {
    float e = s > 0.f ? s : expm1f(s);
    Xn[m * 4096 + o] = f2bf(e);
  }
}

extern "C" void kernel_launch(void* const* d_in, const int* in_sizes, int n_in,
                              void* d_out, int out_size, void* d_ws, size_t ws_size,
                              hipStream_t stream) {
  const float* h   = (const float*)d_in[0];
  const float* Wq  = (const float*)d_in[1];
  const float* bq  = (const float*)d_in[2];
  const float* Wk  = (const float*)d_in[3];
  const float* bk  = (const float*)d_in[4];
  const float* Wv  = (const float*)d_in[5];
  const float* bv  = (const float*)d_in[6];
  const float* W0  = (const float*)d_in[7];
  const float* b0  = (const float*)d_in[8];
  const float* W1  = (const float*)d_in[9];
  const float* b1  = (const float*)d_in[10];
  const float* W2  = (const float*)d_in[11];
  const float* b2  = (const float*)d_in[12];
  const float* Wout= (const float*)d_in[13];
  const float* bout= (const float*)d_in[14];
  float* out = (float*)d_out;

  // workspace layout (floats)
  float* ws    = (float*)d_ws;
  float* big   = ws;                       // 4,194,304 fl: zpart / hbp / Ypart (disjoint lifetimes)
  float* zpart = big;                      // 8*32*4096
  float* hbp   = big;                      // 8*128*4096
  float* Ypart = big;                      // 8*32*4096
  float* z     = ws + 4194304;             // 131072
  float* qt    = z + 131072;               // 524288
  float* qbias = qt + 524288;              // 128
  float* sim   = qbias + 128;              // 65536
  ushort* X0   = (ushort*)(sim + 65536);   // 131072 bf16 each
  ushort* X1   = X0 + 131072;
  ushort* X2   = X1 + 131072;
  ushort* X3   = X2 + 131072;

  float* a_out   = out + 8192;
  float* att_out = out + 139264;

  k_zpart<<<1024, 256, 0, stream>>>(h, zpart);
  k_zfin <<<512, 256, 0, stream>>>(zpart, z);
  k_qt   <<<128, 256, 0, stream>>>(z, Wq, bq, Wk, bk, qt, qbias);
  k_sim  <<<1024, 256, 0, stream>>>(h, qt, qbias, sim);
  k_soft <<<128, 512, 0, stream>>>(sim, att_out);
  k_hbar <<<1024, 256, 0, stream>>>(h, att_out, hbp);
  k_av   <<<128, 256, 0, stream>>>(hbp, Wv, bv, a_out, X0);

  k_pp<4096>        <<<512, 256, 0, stream>>>(X0, W0, Ypart);
  k_ppfin<4096,false><<<512, 256, 0, stream>>>(Ypart, b0, X1, nullptr);
  k_pp<4096>        <<<512, 256, 0, stream>>>(X1, W1, Ypart);
  k_ppfin<4096,false><<<512, 256, 0, stream>>>(Ypart, b1, X2, nullptr);
  k_pp<4096>        <<<512, 256, 0, stream>>>(X2, W2, Ypart);
  k_ppfin<4096,false><<<512, 256, 0, stream>>>(Ypart, b2, X3, nullptr);
  k_pp<256>         <<<32, 256, 0, stream>>>(X3, Wout, Ypart);
  k_ppfin<256,true> <<<32, 256, 0, stream>>>(Ypart, bout, nullptr, out);
}